// Round 1
// baseline (211.184 us; speedup 1.0000x reference)
//
#include <hip/hip_runtime.h>
#include <stdint.h>

// LinearAttention: x[2,8192,1024] -> qkv proj -> per-head softmaxes ->
// context = softmax_n(k)^T v -> out = softmax_d(q) @ ctx -> @ W_out + b.
// All heavy GEMMs in f16 MFMA (16x16x32), small attention math in fp32 scalar.

typedef _Float16 half4 __attribute__((ext_vector_type(4)));
typedef _Float16 half8 __attribute__((ext_vector_type(8)));
typedef float f32x4 __attribute__((ext_vector_type(4)));

// ---- workspace byte offsets (total ~113.6 MB) ----
#define WS_XB 0UL             // x as f16          [16384][1024]   33.55MB
#define WS_WQKVT 33554432UL   // W_qkv^T f16       [1536][1024]     3.15MB
#define WS_WOUTT 36700160UL   // W_out^T f16       [1024][512]      1.05MB
#define WS_QH 37748736UL      // q logits f16      [16][8192][64]  16.78MB
#define WS_KH 54525952UL      // k logits f16      [16][8192][64]  16.78MB
#define WS_VH 71303168UL      // v f16             [16][8192][64]  16.78MB
#define WS_ATTN 88080384UL    // attn out f16      [16384][512]    16.78MB
#define WS_CTXPART 104857600UL// ctx partials f32  [512][4096]      8.39MB
#define WS_COLPART 113246208UL// colsum partials   [512][64]        0.13MB
#define WS_CTX 113377280UL    // ctx f32           [16][64][64]     0.26MB

__device__ __forceinline__ void gld16(const void* g, void* l) {
  // async global->LDS, 16B per lane; LDS dest = wave-uniform base + lane*16
  __builtin_amdgcn_global_load_lds(
      (const __attribute__((address_space(1))) unsigned int*)g,
      (__attribute__((address_space(3))) unsigned int*)l, 16, 0, 0);
}

__global__ void cvt_x_kernel(const float* __restrict__ in,
                             _Float16* __restrict__ out, int n4) {
  int i = blockIdx.x * 256 + threadIdx.x;
  if (i >= n4) return;
  f32x4 v = *(const f32x4*)(in + (size_t)i * 4);
  half4 h = {(_Float16)v[0], (_Float16)v[1], (_Float16)v[2], (_Float16)v[3]};
  *(half4*)(out + (size_t)i * 4) = h;
}

// W[R][C] -> WT[C][R] with f32->f16; coalesced writes, L2 absorbs strided reads
__global__ void transpose_cvt_kernel(const float* __restrict__ W,
                                     _Float16* __restrict__ WT, int logR, int C) {
  int i = blockIdx.x * 256 + threadIdx.x;
  int c = i >> logR;
  int r = i & ((1 << logR) - 1);
  WT[i] = (_Float16)W[(size_t)r * C + c];
}

// m97-style GEMM: 128x128 tile, BK=32, 4 waves, global_load_lds w16.
// A[M][K] row-major, BT[N][K] row-major (B transposed). EPI 0: scatter qkv
// to per-head f16 tensors. EPI 1: +bias, fp32 out, ldc=1024.
template <int EPI>
__global__ __launch_bounds__(256) void gemm_f16(
    const _Float16* __restrict__ A, const _Float16* __restrict__ BT, int K,
    _Float16* __restrict__ oQ, _Float16* __restrict__ oK,
    _Float16* __restrict__ oV, float* __restrict__ oC,
    const float* __restrict__ bias) {
  __shared__ _Float16 sA[128 * 32];
  __shared__ _Float16 sB[128 * 32];
  const int t = threadIdx.x;
  const int w = t >> 6, l = t & 63;
  const int tileN = blockIdx.x, tileM = blockIdx.y;
  const int wr = w >> 1, wc = w & 1;     // wave -> 64x64 quadrant
  const int fr = l & 15, q = l >> 4;

  // staging: wave w covers rows w*32..w*32+31 (2 loads of 16 rows), 4 lanes/row
  const _Float16* Ag = A + (size_t)(tileM * 128 + w * 32 + (l >> 2)) * K + (l & 3) * 8;
  const _Float16* Bg = BT + (size_t)(tileN * 128 + w * 32 + (l >> 2)) * K + (l & 3) * 8;
  _Float16* sAw = &sA[w * 1024];
  _Float16* sBw = &sB[w * 1024];

  f32x4 acc[4][4] = {};

  for (int kt = 0; kt < K; kt += 32) {
    __syncthreads();  // protect LDS from previous iter's readers
    gld16(Ag + kt, sAw);
    gld16(Ag + kt + (size_t)16 * K, sAw + 512);
    gld16(Bg + kt, sBw);
    gld16(Bg + kt + (size_t)16 * K, sBw + 512);
    __syncthreads();  // compiler drains vmcnt before barrier
    half8 af[4], bf[4];
#pragma unroll
    for (int i = 0; i < 4; ++i) {
      af[i] = *(const half8*)&sA[(wr * 64 + i * 16 + fr) * 32 + q * 8];
      bf[i] = *(const half8*)&sB[(wc * 64 + i * 16 + fr) * 32 + q * 8];
    }
#pragma unroll
    for (int mi = 0; mi < 4; ++mi)
#pragma unroll
      for (int ni = 0; ni < 4; ++ni)
        acc[mi][ni] =
            __builtin_amdgcn_mfma_f32_16x16x32_f16(af[mi], bf[ni], acc[mi][ni], 0, 0, 0);
  }

  // C/D layout: col = lane&15, row = (lane>>4)*4 + reg
  if (EPI == 0) {
#pragma unroll
    for (int mi = 0; mi < 4; ++mi) {
      const int grow = tileM * 128 + wr * 64 + mi * 16 + q * 4;
      const int b = grow >> 13, n = grow & 8191;
#pragma unroll
      for (int ni = 0; ni < 4; ++ni) {
        const int gcol = tileN * 128 + wc * 64 + ni * 16 + fr;
        const int which = gcol >> 9, h = (gcol >> 6) & 7, d = gcol & 63;
        _Float16* dst = (which == 0) ? oQ : ((which == 1) ? oK : oV);
        const size_t base = ((size_t)((b << 3) + h) * 8192 + n) * 64 + d;
#pragma unroll
        for (int r = 0; r < 4; ++r)
          dst[base + (size_t)r * 64] = (_Float16)acc[mi][ni][r];
      }
    }
  } else {
#pragma unroll
    for (int mi = 0; mi < 4; ++mi) {
      const int grow = tileM * 128 + wr * 64 + mi * 16 + q * 4;
#pragma unroll
      for (int ni = 0; ni < 4; ++ni) {
        const int gcol = tileN * 128 + wc * 64 + ni * 16 + fr;
        const float bb = bias[gcol];
#pragma unroll
        for (int r = 0; r < 4; ++r)
          oC[(size_t)(grow + r) * 1024 + gcol] = acc[mi][ni][r] + bb;
      }
    }
  }
}

// Per (bh, 256-row chunk): stage exp(k) and v (f16->f32) in LDS, accumulate
// 64x64 partial ctx + per-column partial sums. No atomics -> deterministic.
__global__ __launch_bounds__(256) void ctx_partial_kernel(
    const _Float16* __restrict__ kh, const _Float16* __restrict__ vh,
    float* __restrict__ ctxpart, float* __restrict__ colpart) {
  __shared__ float se[128 * 64];
  __shared__ float sv[128 * 64];
  const int t = threadIdx.x;
  const int bh = blockIdx.x >> 5, ch = blockIdx.x & 31;
  const size_t rowbase = ((size_t)bh * 8192 + ch * 256) * 64;
  const int d0 = (t & 15) * 4, e0 = (t >> 4) * 4;
  float acc[4][4] = {};
  float colacc = 0.f;
  for (int sub = 0; sub < 2; ++sub) {
    const _Float16* kp = kh + rowbase + (size_t)sub * (128 * 64);
    const _Float16* vp = vh + rowbase + (size_t)sub * (128 * 64);
    __syncthreads();
    for (int i = t; i < 2048; i += 256) {
      half4 a = ((const half4*)kp)[i];
      half4 b = ((const half4*)vp)[i];
      f32x4 fa = {__expf((float)a[0]), __expf((float)a[1]),
                  __expf((float)a[2]), __expf((float)a[3])};
      f32x4 fb = {(float)b[0], (float)b[1], (float)b[2], (float)b[3]};
      *(f32x4*)&se[i * 4] = fa;
      *(f32x4*)&sv[i * 4] = fb;
    }
    __syncthreads();
    if (t < 64) {
      for (int n = 0; n < 128; ++n) colacc += se[n * 64 + t];
    }
    for (int n = 0; n < 128; ++n) {
      f32x4 a = *(const f32x4*)&se[n * 64 + d0];
      f32x4 b = *(const f32x4*)&sv[n * 64 + e0];
#pragma unroll
      for (int i2 = 0; i2 < 4; ++i2)
#pragma unroll
        for (int j = 0; j < 4; ++j) acc[i2][j] += a[i2] * b[j];
    }
  }
  float* cp = ctxpart + (size_t)blockIdx.x * 4096;
#pragma unroll
  for (int i2 = 0; i2 < 4; ++i2)
#pragma unroll
    for (int j = 0; j < 4; ++j) cp[(d0 + i2) * 64 + e0 + j] = acc[i2][j];
  if (t < 64) colpart[blockIdx.x * 64 + t] = colacc;
}

// ctx[bh][d][e] = (sum_c ctxpart) / (sum_c colpart[d])
__global__ void ctx_reduce_kernel(const float* __restrict__ ctxpart,
                                  const float* __restrict__ colpart,
                                  float* __restrict__ ctx) {
  int i = blockIdx.x * 256 + threadIdx.x;  // 65536 total
  int bh = i >> 12, r = i & 4095, d = r >> 6;
  float s = 0.f, v = 0.f;
  for (int c = 0; c < 32; ++c) {
    s += colpart[((size_t)bh * 32 + c) * 64 + d];
    v += ctxpart[((size_t)bh * 32 + c) * 4096 + r];
  }
  ctx[i] = v / s;
}

// Per (bh, 128-row chunk): stage q logits, softmax rows in LDS (wave=row),
// then out[n][e] = sum_d softq[n][d]*ctx[d][e]; write attn f16 [16384][512].
__global__ __launch_bounds__(256) void qctx_kernel(const _Float16* __restrict__ qh,
                                                   const float* __restrict__ ctx,
                                                   _Float16* __restrict__ attn) {
  __shared__ float sq[128 * 64];
  __shared__ float sc[64 * 64];
  const int t = threadIdx.x;
  const int bh = blockIdx.x >> 6, ch = blockIdx.x & 63;
  const int b = bh >> 3, h = bh & 7;
  const _Float16* qb = qh + ((size_t)bh * 8192 + ch * 128) * 64;
  for (int i = t; i < 2048; i += 256) {
    half4 a = ((const half4*)qb)[i];
    f32x4 f = {(float)a[0], (float)a[1], (float)a[2], (float)a[3]};
    *(f32x4*)&sq[i * 4] = f;
  }
  const float* cb = ctx + (size_t)bh * 4096;
  for (int i = t; i < 1024; i += 256)
    *(f32x4*)&sc[i * 4] = *(const f32x4*)&cb[i * 4];
  __syncthreads();
  const int w = t >> 6, l = t & 63;
  for (int r = w * 32; r < w * 32 + 32; ++r) {
    float e = __expf(sq[r * 64 + l]);
    float s = e;
#pragma unroll
    for (int off = 1; off < 64; off <<= 1) s += __shfl_xor(s, off, 64);
    sq[r * 64 + l] = e / s;
  }
  __syncthreads();
  const int e0 = (t & 15) * 4, n0 = (t >> 4) * 8;
  float acc[8][4] = {};
  for (int d = 0; d < 64; ++d) {
    f32x4 c4 = *(const f32x4*)&sc[d * 64 + e0];
#pragma unroll
    for (int i = 0; i < 8; ++i) {
      float qv = sq[(n0 + i) * 64 + d];
#pragma unroll
      for (int j = 0; j < 4; ++j) acc[i][j] += qv * c4[j];
    }
  }
#pragma unroll
  for (int i = 0; i < 8; ++i) {
    int n = ch * 128 + n0 + i;
    half4 o = {(_Float16)acc[i][0], (_Float16)acc[i][1], (_Float16)acc[i][2],
               (_Float16)acc[i][3]};
    *(half4*)&attn[(size_t)(b * 8192 + n) * 512 + h * 64 + e0] = o;
  }
}

extern "C" void kernel_launch(void* const* d_in, const int* in_sizes, int n_in,
                              void* d_out, int out_size, void* d_ws, size_t ws_size,
                              hipStream_t stream) {
  const float* x = (const float*)d_in[0];
  const float* Wqkv = (const float*)d_in[1];
  const float* Wout = (const float*)d_in[2];
  const float* bout = (const float*)d_in[3];
  float* out = (float*)d_out;
  char* ws = (char*)d_ws;

  _Float16* xb = (_Float16*)(ws + WS_XB);
  _Float16* wqkvT = (_Float16*)(ws + WS_WQKVT);
  _Float16* woutT = (_Float16*)(ws + WS_WOUTT);
  _Float16* qh = (_Float16*)(ws + WS_QH);
  _Float16* kh = (_Float16*)(ws + WS_KH);
  _Float16* vh = (_Float16*)(ws + WS_VH);
  _Float16* attn = (_Float16*)(ws + WS_ATTN);
  float* ctxpart = (float*)(ws + WS_CTXPART);
  float* colpart = (float*)(ws + WS_COLPART);
  float* ctx = (float*)(ws + WS_CTX);

  // 1) converts
  cvt_x_kernel<<<16384, 256, 0, stream>>>(x, xb, 4194304);
  transpose_cvt_kernel<<<6144, 256, 0, stream>>>(Wqkv, wqkvT, 10, 1536);
  transpose_cvt_kernel<<<2048, 256, 0, stream>>>(Wout, woutT, 9, 1024);
  // 2) qkv projection, scattered to per-head q/k/v
  gemm_f16<0><<<dim3(12, 128), 256, 0, stream>>>(xb, wqkvT, 1024, qh, kh, vh,
                                                 nullptr, nullptr);
  // 3) context = exp(k)^T v partials + colsums, then deterministic reduce
  ctx_partial_kernel<<<512, 256, 0, stream>>>(kh, vh, ctxpart, colpart);
  ctx_reduce_kernel<<<256, 256, 0, stream>>>(ctxpart, colpart, ctx);
  // 4) softmax(q) @ ctx -> attn
  qctx_kernel<<<1024, 256, 0, stream>>>(qh, ctx, attn);
  // 5) output projection + bias
  gemm_f16<1><<<dim3(8, 128), 256, 0, stream>>>(attn, woutT, 512, nullptr, nullptr,
                                                nullptr, out, bout);
}

// Round 3
// 184.872 us; speedup vs baseline: 1.1423x; 1.1423x over previous
//
#include <hip/hip_runtime.h>
#include <stdint.h>

// LinearAttention: x[2,8192,1024] -> qkv proj -> per-head softmaxes ->
// context = softmax_n(k)^T v -> out = softmax_d(q) @ ctx -> @ W_out + b.
// Heavy GEMMs: 256x256 8-phase f16 MFMA template (T1 XCD-swizzle, T2 LDS
// XOR-swizzle, T3/T4 counted vmcnt pipeline, T5 setprio).
//
// Stage schedule (re-derived after R1 race): per iter t2,
//   ph0: stage A0(t2+1) -> other buf   (A halves live until ph2 -> cannot
//   ph1: stage A1(t2+1) -> other buf    stage A into current buf mid-iter)
//   ph2: stage B0(t2+2) -> current buf (B last read at ph1)
//   ph3: stage B1(t2+2) -> current buf; s_waitcnt vmcnt(4) -> tile t2+1 ready
// Per-thread loads: 2 per half-stage; vmcnt(4) leaves only B(t2+2) in flight.

typedef _Float16 half4 __attribute__((ext_vector_type(4)));
typedef _Float16 half8 __attribute__((ext_vector_type(8)));
typedef float f32x4 __attribute__((ext_vector_type(4)));

// ---- workspace byte offsets (total ~113.6 MB) ----
#define WS_XB 0UL             // x as f16          [16384][1024]   33.55MB
#define WS_WQKVT 33554432UL   // W_qkv^T f16       [1536][1024]     3.15MB
#define WS_WOUTT 36700160UL   // W_out^T f16       [1024][512]      1.05MB
#define WS_QH 37748736UL      // q logits f16      [16][8192][64]  16.78MB
#define WS_KH 54525952UL      // k logits f16      [16][8192][64]  16.78MB
#define WS_VH 71303168UL      // v f16             [16][8192][64]  16.78MB
#define WS_ATTN 88080384UL    // attn out f16      [16384][512]    16.78MB
#define WS_CTXPART 104857600UL// ctx partials f32  [512][4096]      8.39MB
#define WS_COLPART 113246208UL// colsum partials   [512][64]        0.13MB
#define WS_CTX 113377280UL    // ctx f32           [16][64][64]     0.26MB

__device__ __forceinline__ void gld16(const void* g, void* l) {
  // async global->LDS, 16B per lane; LDS dest = wave-uniform base + lane*16
  __builtin_amdgcn_global_load_lds(
      (const __attribute__((address_space(1))) unsigned int*)g,
      (__attribute__((address_space(3))) unsigned int*)l, 16, 0, 0);
}

__global__ void cvt_x_kernel(const float* __restrict__ in,
                             _Float16* __restrict__ out, int n4) {
  int i = blockIdx.x * 256 + threadIdx.x;
  if (i >= n4) return;
  f32x4 v = *(const f32x4*)(in + (size_t)i * 4);
  half4 h = {(_Float16)v[0], (_Float16)v[1], (_Float16)v[2], (_Float16)v[3]};
  *(half4*)(out + (size_t)i * 4) = h;
}

// W[R][C] -> WT[C][R] with f32->f16; coalesced writes, L2 absorbs strided reads
__global__ void transpose_cvt_kernel(const float* __restrict__ W,
                                     _Float16* __restrict__ WT, int logR, int C) {
  int i = blockIdx.x * 256 + threadIdx.x;
  int c = i >> logR;
  int r = i & ((1 << logR) - 1);
  WT[i] = (_Float16)W[(size_t)r * C + c];
}

// ---------------- 256x256 8-phase GEMM (m201-style template) ----------------
// A[M][K] f16 row-major, BT[N][K] f16 row-major. 512 threads = 8 waves (2Mx4N),
// per-wave output 128x64. BK=64, LDS = 2 dbuf x (A 32KB + B 32KB) = 128KB.
// LDS tile layout: [256 rows][128 B] with XOR swizzle addr ^= ((row&7)<<4);
// staged linearly via global_load_lds with inverse-swizzled global source.

// stage one half-tile (128 rows x 64 f16) = 2 x global_load_lds(16B)/thread
__device__ __forceinline__ void stage_half(const _Float16* __restrict__ G, int K,
                                           int rowbase, int kt, char* ldsHalf,
                                           int t) {
  const int srow = t >> 3;
  const int scol = ((t & 7) ^ ((t >> 3) & 7)) * 8;  // inverse-swizzled col (f16)
  const int w = t >> 6;
  gld16(G + (size_t)(rowbase + srow) * K + kt + scol, ldsHalf + w * 1024);
  gld16(G + (size_t)(rowbase + 64 + srow) * K + kt + scol,
        ldsHalf + 8192 + w * 1024);
}

#define LGKM0_FENCE()                                      \
  do {                                                     \
    asm volatile("s_waitcnt lgkmcnt(0)" ::: "memory");     \
    __builtin_amdgcn_sched_barrier(0);                     \
  } while (0)

#define PHASE_MFMA(MH, NH)                                                     \
  do {                                                                         \
    __builtin_amdgcn_s_barrier();                                              \
    LGKM0_FENCE();                                                             \
    __builtin_amdgcn_s_setprio(1);                                             \
    _Pragma("unroll") for (int i_ = 0; i_ < 4; ++i_)                           \
        _Pragma("unroll") for (int j_ = 0; j_ < 2; ++j_)                       \
            _Pragma("unroll") for (int kk_ = 0; kk_ < 2; ++kk_)                \
                acc[(MH) * 4 + i_][(NH) * 2 + j_] =                            \
        __builtin_amdgcn_mfma_f32_16x16x32_f16(                                \
            a[i_][kk_], b[(NH) * 2 + j_][kk_],                                 \
            acc[(MH) * 4 + i_][(NH) * 2 + j_], 0, 0, 0);                       \
    __builtin_amdgcn_s_setprio(0);                                             \
  } while (0)

#define LDA_HALF(MH)                                                           \
  do {                                                                         \
    _Pragma("unroll") for (int i_ = 0; i_ < 4; ++i_)                           \
        _Pragma("unroll") for (int kk_ = 0; kk_ < 2; ++kk_) {                  \
      int off_ = (wm * 128 + ((MH) * 4 + i_) * 16 + fr) * 128 + kk_ * 64 +     \
                 qq * 16;                                                      \
      a[i_][kk_] = *(const half8*)(ldsA + (off_ ^ swzx));                      \
    }                                                                          \
  } while (0)

#define LDB_HALF(NH)                                                           \
  do {                                                                         \
    _Pragma("unroll") for (int j_ = 0; j_ < 2; ++j_)                           \
        _Pragma("unroll") for (int kk_ = 0; kk_ < 2; ++kk_) {                  \
      int ni_ = (NH) * 2 + j_;                                                 \
      int off_ = (wn * 64 + ni_ * 16 + fr) * 128 + kk_ * 64 + qq * 16;         \
      b[ni_][kk_] = *(const half8*)(ldsB + (off_ ^ swzx));                     \
    }                                                                          \
  } while (0)

// EPI 0: scatter qkv -> per-head q/k/v f16. EPI 1: +bias, f32 out ldc=1024.
template <int EPI>
__global__ __launch_bounds__(512, 2) void gemm8p(
    const _Float16* __restrict__ A, const _Float16* __restrict__ BT, int K,
    int NTN, _Float16* __restrict__ oQ, _Float16* __restrict__ oK,
    _Float16* __restrict__ oV, float* __restrict__ oC,
    const float* __restrict__ bias) {
  __shared__ char lds[131072];
  const int t = threadIdx.x;
  const int l = t & 63, w = t >> 6;
  const int wm = w >> 2, wn = w & 3;  // wave -> (M half, N quarter)
  const int fr = l & 15, qq = l >> 4;
  const int swzx = (fr & 7) << 4;

  // T1: bijective XCD chunking (nwg % 8 == 0), tileM-major within chunk
  const int nwg = gridDim.x;
  const int cpx = nwg >> 3;
  const int wg = (blockIdx.x & 7) * cpx + (blockIdx.x >> 3);
  const int tileM = wg / NTN, tileN = wg - tileM * NTN;
  const int mbase = tileM * 256, nbase = tileN * 256;

  const int NT = K >> 6;
  f32x4 acc[8][4] = {};
  half8 a[4][2], b[4][2];

  // stage half x of K-tile `tile`: x 0=A0, 3=A1, 1=B0, 2=B1
  auto STG = [&](int tile, int x) {
    int kt = tile * 64;
    if (kt > K - 64) kt = K - 64;  // tail clamp: keep issue counts identical
    char* base = lds + ((tile & 1) << 16);
    if (x == 0)
      stage_half(A, K, mbase, kt, base, t);
    else if (x == 1)
      stage_half(BT, K, nbase, kt, base + 32768, t);
    else if (x == 2)
      stage_half(BT, K, nbase + 128, kt, base + 32768 + 16384, t);
    else
      stage_half(A, K, mbase + 128, kt, base + 16384, t);
  };

  // prologue: all of tile0 (8 loads/thread) + B0,B1 of tile1 (4 loads/thread)
  STG(0, 0); STG(0, 3); STG(0, 1); STG(0, 2);
  STG(1, 1); STG(1, 2);
  asm volatile("s_waitcnt vmcnt(4)" ::: "memory");  // tile0 resident
  __builtin_amdgcn_s_barrier();

  for (int t2 = 0; t2 < NT; ++t2) {
    const char* ldsA = lds + ((t2 & 1) << 16);
    const char* ldsB = ldsA + 32768;
    // ph0: A rows [wm*128, +63], B rows [wn*64, +31]; stage A0(t2+1)->other buf
    LDA_HALF(0);
    LDB_HALF(0);
    STG(t2 + 1, 0);
    PHASE_MFMA(0, 0);
    __builtin_amdgcn_s_barrier();
    // ph1: B rows [wn*64+32, +31]; stage A1(t2+1)->other buf
    LDB_HALF(1);
    STG(t2 + 1, 3);
    PHASE_MFMA(0, 1);
    __builtin_amdgcn_s_barrier();
    // ph2: A rows [wm*128+64, +63]; B fully consumed -> stage B0(t2+2)->cur buf
    LDA_HALF(1);
    STG(t2 + 2, 1);
    PHASE_MFMA(1, 0);
    __builtin_amdgcn_s_barrier();
    // ph3: no frag loads; stage B1(t2+2)->cur buf; counted wait: tile t2+1
    // resident (only B(t2+2)'s 4 loads may remain in flight)
    STG(t2 + 2, 2);
    PHASE_MFMA(1, 1);
    asm volatile("s_waitcnt vmcnt(4)" ::: "memory");
    __builtin_amdgcn_s_barrier();
  }
  asm volatile("s_waitcnt vmcnt(0)" ::: "memory");  // drain tail stages

  // C/D layout: col = lane&15 (=fr), row = (lane>>4)*4 + reg (=qq*4+r)
  if (EPI == 0) {
#pragma unroll
    for (int mi = 0; mi < 8; ++mi) {
      const int grow = mbase + wm * 128 + mi * 16 + qq * 4;
      const int bidx = grow >> 13, n = grow & 8191;
#pragma unroll
      for (int ni = 0; ni < 4; ++ni) {
        const int gcol = nbase + wn * 64 + ni * 16 + fr;
        const int which = gcol >> 9, h = (gcol >> 6) & 7, d = gcol & 63;
        _Float16* dst = (which == 0) ? oQ : ((which == 1) ? oK : oV);
        const size_t base = ((size_t)((bidx << 3) + h) * 8192 + n) * 64 + d;
#pragma unroll
        for (int r = 0; r < 4; ++r)
          dst[base + (size_t)r * 64] = (_Float16)acc[mi][ni][r];
      }
    }
  } else {
#pragma unroll
    for (int mi = 0; mi < 8; ++mi) {
      const int grow = mbase + wm * 128 + mi * 16 + qq * 4;
#pragma unroll
      for (int ni = 0; ni < 4; ++ni) {
        const int gcol = nbase + wn * 64 + ni * 16 + fr;
        const float bb = bias[gcol];
#pragma unroll
        for (int r = 0; r < 4; ++r)
          oC[(size_t)(grow + r) * 1024 + gcol] = acc[mi][ni][r] + bb;
      }
    }
  }
}

// Per (bh, 256-row chunk): stage exp(k) and v (f16->f32) in LDS, accumulate
// 64x64 partial ctx + per-column partial sums. No atomics -> deterministic.
__global__ __launch_bounds__(256) void ctx_partial_kernel(
    const _Float16* __restrict__ kh, const _Float16* __restrict__ vh,
    float* __restrict__ ctxpart, float* __restrict__ colpart) {
  __shared__ float se[128 * 64];
  __shared__ float sv[128 * 64];
  const int t = threadIdx.x;
  const int bh = blockIdx.x >> 5, ch = blockIdx.x & 31;
  const size_t rowbase = ((size_t)bh * 8192 + ch * 256) * 64;
  const int d0 = (t & 15) * 4, e0 = (t >> 4) * 4;
  float acc[4][4] = {};
  float colacc = 0.f;
  for (int sub = 0; sub < 2; ++sub) {
    const _Float16* kp = kh + rowbase + (size_t)sub * (128 * 64);
    const _Float16* vp = vh + rowbase + (size_t)sub * (128 * 64);
    __syncthreads();
    for (int i = t; i < 2048; i += 256) {
      half4 a = ((const half4*)kp)[i];
      half4 b = ((const half4*)vp)[i];
      f32x4 fa = {__expf((float)a[0]), __expf((float)a[1]),
                  __expf((float)a[2]), __expf((float)a[3])};
      f32x4 fb = {(float)b[0], (float)b[1], (float)b[2], (float)b[3]};
      *(f32x4*)&se[i * 4] = fa;
      *(f32x4*)&sv[i * 4] = fb;
    }
    __syncthreads();
    if (t < 64) {
      for (int n = 0; n < 128; ++n) colacc += se[n * 64 + t];
    }
    for (int n = 0; n < 128; ++n) {
      f32x4 a = *(const f32x4*)&se[n * 64 + d0];
      f32x4 b = *(const f32x4*)&sv[n * 64 + e0];
#pragma unroll
      for (int i2 = 0; i2 < 4; ++i2)
#pragma unroll
        for (int j = 0; j < 4; ++j) acc[i2][j] += a[i2] * b[j];
    }
  }
  float* cp = ctxpart + (size_t)blockIdx.x * 4096;
#pragma unroll
  for (int i2 = 0; i2 < 4; ++i2)
#pragma unroll
    for (int j = 0; j < 4; ++j) cp[(d0 + i2) * 64 + e0 + j] = acc[i2][j];
  if (t < 64) colpart[blockIdx.x * 64 + t] = colacc;
}

// ctx[bh][d][e] = (sum_c ctxpart) / (sum_c colpart[d])
__global__ void ctx_reduce_kernel(const float* __restrict__ ctxpart,
                                  const float* __restrict__ colpart,
                                  float* __restrict__ ctx) {
  int i = blockIdx.x * 256 + threadIdx.x;  // 65536 total
  int bh = i >> 12, r = i & 4095, d = r >> 6;
  float s = 0.f, v = 0.f;
  for (int c = 0; c < 32; ++c) {
    s += colpart[((size_t)bh * 32 + c) * 64 + d];
    v += ctxpart[((size_t)bh * 32 + c) * 4096 + r];
  }
  ctx[i] = v / s;
}

// Per (bh, 128-row chunk): stage q logits, softmax rows in LDS (wave=row),
// then out[n][e] = sum_d softq[n][d]*ctx[d][e]; write attn f16 [16384][512].
__global__ __launch_bounds__(256) void qctx_kernel(const _Float16* __restrict__ qh,
                                                   const float* __restrict__ ctx,
                                                   _Float16* __restrict__ attn) {
  __shared__ float sq[128 * 64];
  __shared__ float sc[64 * 64];
  const int t = threadIdx.x;
  const int bh = blockIdx.x >> 6, ch = blockIdx.x & 63;
  const int b = bh >> 3, h = bh & 7;
  const _Float16* qb = qh + ((size_t)bh * 8192 + ch * 128) * 64;
  for (int i = t; i < 2048; i += 256) {
    half4 a = ((const half4*)qb)[i];
    f32x4 f = {(float)a[0], (float)a[1], (float)a[2], (float)a[3]};
    *(f32x4*)&sq[i * 4] = f;
  }
  const float* cb = ctx + (size_t)bh * 4096;
  for (int i = t; i < 1024; i += 256)
    *(f32x4*)&sc[i * 4] = *(const f32x4*)&cb[i * 4];
  __syncthreads();
  const int w = t >> 6, l = t & 63;
  for (int r = w * 32; r < w * 32 + 32; ++r) {
    float e = __expf(sq[r * 64 + l]);
    float s = e;
#pragma unroll
    for (int off = 1; off < 64; off <<= 1) s += __shfl_xor(s, off, 64);
    sq[r * 64 + l] = e / s;
  }
  __syncthreads();
  const int e0 = (t & 15) * 4, n0 = (t >> 4) * 8;
  float acc[8][4] = {};
  for (int d = 0; d < 64; ++d) {
    f32x4 c4 = *(const f32x4*)&sc[d * 64 + e0];
#pragma unroll
    for (int i = 0; i < 8; ++i) {
      float qv = sq[(n0 + i) * 64 + d];
#pragma unroll
      for (int j = 0; j < 4; ++j) acc[i][j] += qv * c4[j];
    }
  }
#pragma unroll
  for (int i = 0; i < 8; ++i) {
    int n = ch * 128 + n0 + i;
    half4 o = {(_Float16)acc[i][0], (_Float16)acc[i][1], (_Float16)acc[i][2],
               (_Float16)acc[i][3]};
    *(half4*)&attn[(size_t)(b * 8192 + n) * 512 + h * 64 + e0] = o;
  }
}

extern "C" void kernel_launch(void* const* d_in, const int* in_sizes, int n_in,
                              void* d_out, int out_size, void* d_ws, size_t ws_size,
                              hipStream_t stream) {
  const float* x = (const float*)d_in[0];
  const float* Wqkv = (const float*)d_in[1];
  const float* Wout = (const float*)d_in[2];
  const float* bout = (const float*)d_in[3];
  float* out = (float*)d_out;
  char* ws = (char*)d_ws;

  _Float16* xb = (_Float16*)(ws + WS_XB);
  _Float16* wqkvT = (_Float16*)(ws + WS_WQKVT);
  _Float16* woutT = (_Float16*)(ws + WS_WOUTT);
  _Float16* qh = (_Float16*)(ws + WS_QH);
  _Float16* kh = (_Float16*)(ws + WS_KH);
  _Float16* vh = (_Float16*)(ws + WS_VH);
  _Float16* attn = (_Float16*)(ws + WS_ATTN);
  float* ctxpart = (float*)(ws + WS_CTXPART);
  float* colpart = (float*)(ws + WS_COLPART);
  float* ctx = (float*)(ws + WS_CTX);

  // 1) converts
  cvt_x_kernel<<<16384, 256, 0, stream>>>(x, xb, 4194304);
  transpose_cvt_kernel<<<6144, 256, 0, stream>>>(Wqkv, wqkvT, 10, 1536);
  transpose_cvt_kernel<<<2048, 256, 0, stream>>>(Wout, woutT, 9, 1024);
  // 2) qkv projection (M=16384,N=1536,K=1024), scattered to per-head q/k/v
  gemm8p<0><<<384, 512, 0, stream>>>(xb, wqkvT, 1024, 6, qh, kh, vh, nullptr,
                                     nullptr);
  // 3) context = exp(k)^T v partials + colsums, then deterministic reduce
  ctx_partial_kernel<<<512, 256, 0, stream>>>(kh, vh, ctxpart, colpart);
  ctx_reduce_kernel<<<256, 256, 0, stream>>>(ctxpart, colpart, ctx);
  // 4) softmax(q) @ ctx -> attn
  qctx_kernel<<<1024, 256, 0, stream>>>(qh, ctx, attn);
  // 5) output projection + bias (M=16384,N=1024,K=512)
  gemm8p<1><<<256, 512, 0, stream>>>(attn, woutT, 512, 4, nullptr, nullptr,
                                     nullptr, out, bout);
}

// Round 4
// 179.012 us; speedup vs baseline: 1.1797x; 1.0327x over previous
//
#include <hip/hip_runtime.h>
#include <stdint.h>

// LinearAttention: x[2,8192,1024] -> qkv proj -> per-head softmaxes ->
// context = softmax_n(k)^T v -> out = softmax_d(q) @ ctx -> @ W_out + b.
// Heavy GEMMs: 256x256 8-phase f16 MFMA template (T1 XCD-swizzle, T2 LDS
// XOR-swizzle, T3/T4 counted vmcnt pipeline, T5 setprio).
//
// R4 change vs R3: dropped the manual lgkmcnt(0)+sched_barrier(0) fence in
// each phase. ds_reads are compiler-visible, so the scoreboard inserts
// counted lgkmcnt waits -> ds_read drain overlaps MFMA issue (R3 serialized
// them; 5570 cyc/K-tile observed vs 2640 MFMA floor). Stage schedule,
// barriers, vmcnt discipline unchanged (verified race-free in R3).
//
// Stage schedule: per iter t2,
//   ph0: stage A0(t2+1) -> other buf   (A halves live until ph2)
//   ph1: stage A1(t2+1) -> other buf
//   ph2: stage B0(t2+2) -> current buf (B last read at ph1)
//   ph3: stage B1(t2+2) -> current buf; s_waitcnt vmcnt(4) -> tile t2+1 ready

typedef _Float16 half4 __attribute__((ext_vector_type(4)));
typedef _Float16 half8 __attribute__((ext_vector_type(8)));
typedef float f32x4 __attribute__((ext_vector_type(4)));

// ---- workspace byte offsets (total ~113.6 MB) ----
#define WS_XB 0UL             // x as f16          [16384][1024]   33.55MB
#define WS_WQKVT 33554432UL   // W_qkv^T f16       [1536][1024]     3.15MB
#define WS_WOUTT 36700160UL   // W_out^T f16       [1024][512]      1.05MB
#define WS_QH 37748736UL      // q logits f16      [16][8192][64]  16.78MB
#define WS_KH 54525952UL      // k logits f16      [16][8192][64]  16.78MB
#define WS_VH 71303168UL      // v f16             [16][8192][64]  16.78MB
#define WS_ATTN 88080384UL    // attn out f16      [16384][512]    16.78MB
#define WS_CTXPART 104857600UL// ctx partials f32  [512][4096]      8.39MB
#define WS_COLPART 113246208UL// colsum partials   [512][64]        0.13MB
#define WS_CTX 113377280UL    // ctx f32           [16][64][64]     0.26MB

__device__ __forceinline__ void gld16(const void* g, void* l) {
  // async global->LDS, 16B per lane; LDS dest = wave-uniform base + lane*16
  __builtin_amdgcn_global_load_lds(
      (const __attribute__((address_space(1))) unsigned int*)g,
      (__attribute__((address_space(3))) unsigned int*)l, 16, 0, 0);
}

// Fused prep: cvt x (f32->f16), transpose+cvt W_qkv, transpose+cvt W_out.
// One launch instead of three (fewer graph-replay gaps).
__global__ void prep_kernel(const float* __restrict__ x,
                            const float* __restrict__ Wqkv,
                            const float* __restrict__ Wout,
                            _Float16* __restrict__ xb,
                            _Float16* __restrict__ wqkvT,
                            _Float16* __restrict__ woutT) {
  const int blk = blockIdx.x;
  if (blk < 16384) {
    int i = blk * 256 + threadIdx.x;  // 4 f32 per thread
    f32x4 v = *(const f32x4*)(x + (size_t)i * 4);
    half4 h = {(_Float16)v[0], (_Float16)v[1], (_Float16)v[2], (_Float16)v[3]};
    *(half4*)(xb + (size_t)i * 4) = h;
  } else if (blk < 16384 + 6144) {
    int i = (blk - 16384) * 256 + threadIdx.x;  // [0, 1536*1024)
    int c = i >> 10, r = i & 1023;
    wqkvT[i] = (_Float16)Wqkv[(size_t)r * 1536 + c];
  } else {
    int i = (blk - 16384 - 6144) * 256 + threadIdx.x;  // [0, 1024*512)
    int c = i >> 9, r = i & 511;
    woutT[i] = (_Float16)Wout[(size_t)r * 1024 + c];
  }
}

// ---------------- 256x256 8-phase GEMM (m201-style template) ----------------
// A[M][K] f16 row-major, BT[N][K] f16 row-major. 512 threads = 8 waves (2Mx4N),
// per-wave output 128x64. BK=64, LDS = 2 dbuf x (A 32KB + B 32KB) = 128KB.
// LDS tile layout: [256 rows][128 B] with XOR swizzle addr ^= ((row&7)<<4);
// staged linearly via global_load_lds with inverse-swizzled global source.

// stage one half-tile (128 rows x 64 f16) = 2 x global_load_lds(16B)/thread
__device__ __forceinline__ void stage_half(const _Float16* __restrict__ G, int K,
                                           int rowbase, int kt, char* ldsHalf,
                                           int t) {
  const int srow = t >> 3;
  const int scol = ((t & 7) ^ ((t >> 3) & 7)) * 8;  // inverse-swizzled col (f16)
  const int w = t >> 6;
  gld16(G + (size_t)(rowbase + srow) * K + kt + scol, ldsHalf + w * 1024);
  gld16(G + (size_t)(rowbase + 64 + srow) * K + kt + scol,
        ldsHalf + 8192 + w * 1024);
}

// No manual lgkmcnt fence: frag loads are compiler-visible; the scoreboard
// emits counted lgkmcnt waits so MFMA issue overlaps the ds_read drain.
#define PHASE_MFMA(MH, NH)                                                     \
  do {                                                                         \
    __builtin_amdgcn_s_barrier();                                              \
    __builtin_amdgcn_s_setprio(1);                                             \
    _Pragma("unroll") for (int i_ = 0; i_ < 4; ++i_)                           \
        _Pragma("unroll") for (int j_ = 0; j_ < 2; ++j_)                       \
            _Pragma("unroll") for (int kk_ = 0; kk_ < 2; ++kk_)                \
                acc[(MH) * 4 + i_][(NH) * 2 + j_] =                            \
        __builtin_amdgcn_mfma_f32_16x16x32_f16(                                \
            a[i_][kk_], b[(NH) * 2 + j_][kk_],                                 \
            acc[(MH) * 4 + i_][(NH) * 2 + j_], 0, 0, 0);                       \
    __builtin_amdgcn_s_setprio(0);                                             \
  } while (0)

#define LDA_HALF(MH)                                                           \
  do {                                                                         \
    _Pragma("unroll") for (int i_ = 0; i_ < 4; ++i_)                           \
        _Pragma("unroll") for (int kk_ = 0; kk_ < 2; ++kk_) {                  \
      int off_ = (wm * 128 + ((MH) * 4 + i_) * 16 + fr) * 128 + kk_ * 64 +     \
                 qq * 16;                                                      \
      a[i_][kk_] = *(const half8*)(ldsA + (off_ ^ swzx));                      \
    }                                                                          \
  } while (0)

#define LDB_HALF(NH)                                                           \
  do {                                                                         \
    _Pragma("unroll") for (int j_ = 0; j_ < 2; ++j_)                           \
        _Pragma("unroll") for (int kk_ = 0; kk_ < 2; ++kk_) {                  \
      int ni_ = (NH) * 2 + j_;                                                 \
      int off_ = (wn * 64 + ni_ * 16 + fr) * 128 + kk_ * 64 + qq * 16;         \
      b[ni_][kk_] = *(const half8*)(ldsB + (off_ ^ swzx));                     \
    }                                                                          \
  } while (0)

// EPI 0: scatter qkv -> per-head q/k/v f16. EPI 1: +bias, f32 out ldc=1024.
template <int EPI>
__global__ __launch_bounds__(512, 2) void gemm8p(
    const _Float16* __restrict__ A, const _Float16* __restrict__ BT, int K,
    int NTN, _Float16* __restrict__ oQ, _Float16* __restrict__ oK,
    _Float16* __restrict__ oV, float* __restrict__ oC,
    const float* __restrict__ bias) {
  __shared__ char lds[131072];
  const int t = threadIdx.x;
  const int l = t & 63, w = t >> 6;
  const int wm = w >> 2, wn = w & 3;  // wave -> (M half, N quarter)
  const int fr = l & 15, qq = l >> 4;
  const int swzx = (fr & 7) << 4;

  // T1: bijective XCD chunking (nwg % 8 == 0), tileM-major within chunk
  const int nwg = gridDim.x;
  const int cpx = nwg >> 3;
  const int wg = (blockIdx.x & 7) * cpx + (blockIdx.x >> 3);
  const int tileM = wg / NTN, tileN = wg - tileM * NTN;
  const int mbase = tileM * 256, nbase = tileN * 256;

  const int NT = K >> 6;
  f32x4 acc[8][4] = {};
  half8 a[4][2], b[4][2];

  // stage half x of K-tile `tile`: x 0=A0, 3=A1, 1=B0, 2=B1
  auto STG = [&](int tile, int x) {
    int kt = tile * 64;
    if (kt > K - 64) kt = K - 64;  // tail clamp: keep issue counts identical
    char* base = lds + ((tile & 1) << 16);
    if (x == 0)
      stage_half(A, K, mbase, kt, base, t);
    else if (x == 1)
      stage_half(BT, K, nbase, kt, base + 32768, t);
    else if (x == 2)
      stage_half(BT, K, nbase + 128, kt, base + 32768 + 16384, t);
    else
      stage_half(A, K, mbase + 128, kt, base + 16384, t);
  };

  // prologue: all of tile0 (8 loads/thread) + B0,B1 of tile1 (4 loads/thread)
  STG(0, 0); STG(0, 3); STG(0, 1); STG(0, 2);
  STG(1, 1); STG(1, 2);
  asm volatile("s_waitcnt vmcnt(4)" ::: "memory");  // tile0 resident
  __builtin_amdgcn_s_barrier();

  for (int t2 = 0; t2 < NT; ++t2) {
    const char* ldsA = lds + ((t2 & 1) << 16);
    const char* ldsB = ldsA + 32768;
    // ph0: A rows [wm*128, +63], B rows [wn*64, +31]; stage A0(t2+1)->other buf
    LDA_HALF(0);
    LDB_HALF(0);
    STG(t2 + 1, 0);
    PHASE_MFMA(0, 0);
    __builtin_amdgcn_s_barrier();
    // ph1: B rows [wn*64+32, +31]; stage A1(t2+1)->other buf
    LDB_HALF(1);
    STG(t2 + 1, 3);
    PHASE_MFMA(0, 1);
    __builtin_amdgcn_s_barrier();
    // ph2: A rows [wm*128+64, +63]; B fully consumed -> stage B0(t2+2)->cur buf
    LDA_HALF(1);
    STG(t2 + 2, 1);
    PHASE_MFMA(1, 0);
    __builtin_amdgcn_s_barrier();
    // ph3: no frag loads; stage B1(t2+2)->cur buf; counted wait: tile t2+1
    // resident (only B(t2+2)'s 4 loads may remain in flight)
    STG(t2 + 2, 2);
    PHASE_MFMA(1, 1);
    asm volatile("s_waitcnt vmcnt(4)" ::: "memory");
    __builtin_amdgcn_s_barrier();
  }
  asm volatile("s_waitcnt vmcnt(0)" ::: "memory");  // drain tail stages

  // C/D layout: col = lane&15 (=fr), row = (lane>>4)*4 + reg (=qq*4+r)
  if (EPI == 0) {
#pragma unroll
    for (int mi = 0; mi < 8; ++mi) {
      const int grow = mbase + wm * 128 + mi * 16 + qq * 4;
      const int bidx = grow >> 13, n = grow & 8191;
#pragma unroll
      for (int ni = 0; ni < 4; ++ni) {
        const int gcol = nbase + wn * 64 + ni * 16 + fr;
        const int which = gcol >> 9, h = (gcol >> 6) & 7, d = gcol & 63;
        _Float16* dst = (which == 0) ? oQ : ((which == 1) ? oK : oV);
        const size_t base = ((size_t)((bidx << 3) + h) * 8192 + n) * 64 + d;
#pragma unroll
        for (int r = 0; r < 4; ++r)
          dst[base + (size_t)r * 64] = (_Float16)acc[mi][ni][r];
      }
    }
  } else {
#pragma unroll
    for (int mi = 0; mi < 8; ++mi) {
      const int grow = mbase + wm * 128 + mi * 16 + qq * 4;
#pragma unroll
      for (int ni = 0; ni < 4; ++ni) {
        const int gcol = nbase + wn * 64 + ni * 16 + fr;
        const float bb = bias[gcol];
#pragma unroll
        for (int r = 0; r < 4; ++r)
          oC[(size_t)(grow + r) * 1024 + gcol] = acc[mi][ni][r] + bb;
      }
    }
  }
}

// Per (bh, 256-row chunk): stage exp(k) and v (f16->f32) in LDS, accumulate
// 64x64 partial ctx + per-column partial sums. No atomics -> deterministic.
__global__ __launch_bounds__(256) void ctx_partial_kernel(
    const _Float16* __restrict__ kh, const _Float16* __restrict__ vh,
    float* __restrict__ ctxpart, float* __restrict__ colpart) {
  __shared__ float se[128 * 64];
  __shared__ float sv[128 * 64];
  const int t = threadIdx.x;
  const int bh = blockIdx.x >> 5, ch = blockIdx.x & 31;
  const size_t rowbase = ((size_t)bh * 8192 + ch * 256) * 64;
  const int d0 = (t & 15) * 4, e0 = (t >> 4) * 4;
  float acc[4][4] = {};
  float colacc = 0.f;
  for (int sub = 0; sub < 2; ++sub) {
    const _Float16* kp = kh + rowbase + (size_t)sub * (128 * 64);
    const _Float16* vp = vh + rowbase + (size_t)sub * (128 * 64);
    __syncthreads();
    for (int i = t; i < 2048; i += 256) {
      half4 a = ((const half4*)kp)[i];
      half4 b = ((const half4*)vp)[i];
      f32x4 fa = {__expf((float)a[0]), __expf((float)a[1]),
                  __expf((float)a[2]), __expf((float)a[3])};
      f32x4 fb = {(float)b[0], (float)b[1], (float)b[2], (float)b[3]};
      *(f32x4*)&se[i * 4] = fa;
      *(f32x4*)&sv[i * 4] = fb;
    }
    __syncthreads();
    if (t < 64) {
      for (int n = 0; n < 128; ++n) colacc += se[n * 64 + t];
    }
    for (int n = 0; n < 128; ++n) {
      f32x4 a = *(const f32x4*)&se[n * 64 + d0];
      f32x4 b = *(const f32x4*)&sv[n * 64 + e0];
#pragma unroll
      for (int i2 = 0; i2 < 4; ++i2)
#pragma unroll
        for (int j = 0; j < 4; ++j) acc[i2][j] += a[i2] * b[j];
    }
  }
  float* cp = ctxpart + (size_t)blockIdx.x * 4096;
#pragma unroll
  for (int i2 = 0; i2 < 4; ++i2)
#pragma unroll
    for (int j = 0; j < 4; ++j) cp[(d0 + i2) * 64 + e0 + j] = acc[i2][j];
  if (t < 64) colpart[blockIdx.x * 64 + t] = colacc;
}

// ctx[bh][d][e] = (sum_c ctxpart) / (sum_c colpart[d])
__global__ void ctx_reduce_kernel(const float* __restrict__ ctxpart,
                                  const float* __restrict__ colpart,
                                  float* __restrict__ ctx) {
  int i = blockIdx.x * 256 + threadIdx.x;  // 65536 total
  int bh = i >> 12, r = i & 4095, d = r >> 6;
  float s = 0.f, v = 0.f;
  for (int c = 0; c < 32; ++c) {
    s += colpart[((size_t)bh * 32 + c) * 64 + d];
    v += ctxpart[((size_t)bh * 32 + c) * 4096 + r];
  }
  ctx[i] = v / s;
}

// Per (bh, 128-row chunk): stage q logits, softmax rows in LDS (wave=row),
// then out[n][e] = sum_d softq[n][d]*ctx[d][e]; write attn f16 [16384][512].
__global__ __launch_bounds__(256) void qctx_kernel(const _Float16* __restrict__ qh,
                                                   const float* __restrict__ ctx,
                                                   _Float16* __restrict__ attn) {
  __shared__ float sq[128 * 64];
  __shared__ float sc[64 * 64];
  const int t = threadIdx.x;
  const int bh = blockIdx.x >> 6, ch = blockIdx.x & 63;
  const int b = bh >> 3, h = bh & 7;
  const _Float16* qb = qh + ((size_t)bh * 8192 + ch * 128) * 64;
  for (int i = t; i < 2048; i += 256) {
    half4 a = ((const half4*)qb)[i];
    f32x4 f = {(float)a[0], (float)a[1], (float)a[2], (float)a[3]};
    *(f32x4*)&sq[i * 4] = f;
  }
  const float* cb = ctx + (size_t)bh * 4096;
  for (int i = t; i < 1024; i += 256)
    *(f32x4*)&sc[i * 4] = *(const f32x4*)&cb[i * 4];
  __syncthreads();
  const int w = t >> 6, l = t & 63;
  for (int r = w * 32; r < w * 32 + 32; ++r) {
    float e = __expf(sq[r * 64 + l]);
    float s = e;
#pragma unroll
    for (int off = 1; off < 64; off <<= 1) s += __shfl_xor(s, off, 64);
    sq[r * 64 + l] = e / s;
  }
  __syncthreads();
  const int e0 = (t & 15) * 4, n0 = (t >> 4) * 8;
  float acc[8][4] = {};
  for (int d = 0; d < 64; ++d) {
    f32x4 c4 = *(const f32x4*)&sc[d * 64 + e0];
#pragma unroll
    for (int i = 0; i < 8; ++i) {
      float qv = sq[(n0 + i) * 64 + d];
#pragma unroll
      for (int j = 0; j < 4; ++j) acc[i][j] += qv * c4[j];
    }
  }
#pragma unroll
  for (int i = 0; i < 8; ++i) {
    int n = ch * 128 + n0 + i;
    half4 o = {(_Float16)acc[i][0], (_Float16)acc[i][1], (_Float16)acc[i][2],
               (_Float16)acc[i][3]};
    *(half4*)&attn[(size_t)(b * 8192 + n) * 512 + h * 64 + e0] = o;
  }
}

extern "C" void kernel_launch(void* const* d_in, const int* in_sizes, int n_in,
                              void* d_out, int out_size, void* d_ws, size_t ws_size,
                              hipStream_t stream) {
  const float* x = (const float*)d_in[0];
  const float* Wqkv = (const float*)d_in[1];
  const float* Wout = (const float*)d_in[2];
  const float* bout = (const float*)d_in[3];
  float* out = (float*)d_out;
  char* ws = (char*)d_ws;

  _Float16* xb = (_Float16*)(ws + WS_XB);
  _Float16* wqkvT = (_Float16*)(ws + WS_WQKVT);
  _Float16* woutT = (_Float16*)(ws + WS_WOUTT);
  _Float16* qh = (_Float16*)(ws + WS_QH);
  _Float16* kh = (_Float16*)(ws + WS_KH);
  _Float16* vh = (_Float16*)(ws + WS_VH);
  _Float16* attn = (_Float16*)(ws + WS_ATTN);
  float* ctxpart = (float*)(ws + WS_CTXPART);
  float* colpart = (float*)(ws + WS_COLPART);
  float* ctx = (float*)(ws + WS_CTX);

  // 1) fused converts (x cvt + both weight transposes)
  prep_kernel<<<24576, 256, 0, stream>>>(x, Wqkv, Wout, xb, wqkvT, woutT);
  // 2) qkv projection (M=16384,N=1536,K=1024), scattered to per-head q/k/v
  gemm8p<0><<<384, 512, 0, stream>>>(xb, wqkvT, 1024, 6, qh, kh, vh, nullptr,
                                     nullptr);
  // 3) context = exp(k)^T v partials + colsums, then deterministic reduce
  ctx_partial_kernel<<<512, 256, 0, stream>>>(kh, vh, ctxpart, colpart);
  ctx_reduce_kernel<<<256, 256, 0, stream>>>(ctxpart, colpart, ctx);
  // 4) softmax(q) @ ctx -> attn
  qctx_kernel<<<1024, 256, 0, stream>>>(qh, ctx, attn);
  // 5) output projection + bias (M=16384,N=1024,K=512)
  gemm8p<1><<<256, 512, 0, stream>>>(attn, woutT, 512, 4, nullptr, nullptr,
                                     nullptr, out, bout);
}